// Round 5
// baseline (2354.893 us; speedup 1.0000x reference)
//
#include <hip/hip_runtime.h>
#include <math.h>

#define NN 30000
#define NE 960000
#define HID 256
#define NH 4
#define HD 64

typedef __attribute__((ext_vector_type(8))) __bf16 bf16x8;
typedef __attribute__((ext_vector_type(4))) float f32x4;
typedef __attribute__((ext_vector_type(4))) unsigned int u32x4;
typedef __attribute__((ext_vector_type(4))) unsigned short u16x4;

__device__ __forceinline__ unsigned short f2bf(float f) {
    unsigned u = __builtin_bit_cast(unsigned, f);
    u += 0x7fffu + ((u >> 16) & 1u);          // round-to-nearest-even
    return (unsigned short)(u >> 16);
}
__device__ __forceinline__ float bf2f(unsigned short h) {
    unsigned u = ((unsigned)h) << 16;
    return __builtin_bit_cast(float, u);
}

// ---------------------------------------------------------------------------
// Weight split+transpose: W (K x N fp32, row-major) -> Wh/Wl (N x K bf16,
// row-major, k contiguous).  W = Wh + Wl to ~2^-17 relative.
// ---------------------------------------------------------------------------
__global__ void wsplit_k(const float* __restrict__ W, int K, int N,
                         unsigned short* __restrict__ Wh,
                         unsigned short* __restrict__ Wl)
{
    const int gid = blockIdx.x * 256 + threadIdx.x;
    if (gid >= K * N) return;
    const int k = gid / N, n = gid - k * N;
    const float f = W[gid];
    const unsigned short h = f2bf(f);
    const float lo = f - bf2f(h);
    Wh[(size_t)n * K + k] = h;
    Wl[(size_t)n * K + k] = f2bf(lo);
}

// ---------------------------------------------------------------------------
// bf16-split MFMA GEMM: C = A@W + epilogue, fp32 in/out, internally
// A@W ~= Ah@Wh + Ah@Wl + Al@Wh via v_mfma_f32_16x16x32_bf16 (fp32 accum).
// Tile 128x128, BK=32, 256 threads = 4 waves in 2x2, each wave 64x64
// (4x4 fragments of 16x16).
// mode 0: C = A@W + bias
// mode 1: C = leaky(gamma*(A@W+bias)*invs + beta2, a)
// mode 2: C += leaky(...)
// Requires: K % 32 == 0, N % 128 == 0 (true for all call sites).
// ---------------------------------------------------------------------------
#define TBM 128
#define TBN 128
#define TBK 32
#define LDK 40   // padded k-stride (elements): 80 B rows, 16B-aligned, ~2-way banks

__global__ void __launch_bounds__(256) gemm_mfma(
    const float* __restrict__ A,
    const unsigned short* __restrict__ Wth,   // N x K bf16 hi
    const unsigned short* __restrict__ Wtl,   // N x K bf16 lo
    const float* __restrict__ bias,
    const float* __restrict__ gamma, const float* __restrict__ beta2,
    const float* __restrict__ a_ptr,
    float* __restrict__ C, int M, int N, int K, int mode)
{
    __shared__ unsigned short Ah[TBM * LDK];
    __shared__ unsigned short Al[TBM * LDK];
    __shared__ unsigned short Bh[TBN * LDK];
    __shared__ unsigned short Bl[TBN * LDK];

    const int t = threadIdx.x;
    const int bm = blockIdx.y * TBM;
    const int bn = blockIdx.x * TBN;
    const int wid = t >> 6, lane = t & 63;
    const int wm = (wid >> 1) * 64;           // wave row offset in tile
    const int wn = (wid & 1) * 64;            // wave col offset in tile
    const int fr = lane & 15;                 // fragment row/col within 16
    const int kg = lane >> 4;                 // k-group 0..3 (8 k each)

    const int arow = t >> 3;                  // 0..31  (A staging)
    const int ak   = (t & 7) * 4;             // 0..28

    f32x4 acc[4][4] = {};

    for (int k0 = 0; k0 < K; k0 += TBK) {
        // ---- stage A tile (fp32 -> bf16 hi/lo) ----
#pragma unroll
        for (int r = 0; r < 4; r++) {
            const int row = r * 32 + arow;
            const int gr = bm + row;
            float4 av = make_float4(0.f, 0.f, 0.f, 0.f);
            if (gr < M) av = *(const float4*)(A + (size_t)gr * K + k0 + ak);
            const unsigned short h0 = f2bf(av.x), h1 = f2bf(av.y),
                                 h2 = f2bf(av.z), h3 = f2bf(av.w);
            const unsigned short l0 = f2bf(av.x - bf2f(h0)),
                                 l1 = f2bf(av.y - bf2f(h1)),
                                 l2 = f2bf(av.z - bf2f(h2)),
                                 l3 = f2bf(av.w - bf2f(h3));
            u16x4 hv; hv.x = h0; hv.y = h1; hv.z = h2; hv.w = h3;
            u16x4 lv; lv.x = l0; lv.y = l1; lv.z = l2; lv.w = l3;
            *(u16x4*)&Ah[row * LDK + ak] = hv;
            *(u16x4*)&Al[row * LDK + ak] = lv;
        }
        // ---- stage B tile (already bf16, transposed [n][k]) ----
#pragma unroll
        for (int i2 = 0; i2 < 2; i2++) {
            const int i = i2 * 256 + t;
            const int n = i >> 2, kc = (i & 3) * 8;
            const size_t g = (size_t)(bn + n) * K + k0 + kc;
            *(u32x4*)&Bh[n * LDK + kc] = *(const u32x4*)&Wth[g];
            *(u32x4*)&Bl[n * LDK + kc] = *(const u32x4*)&Wtl[g];
        }
        __syncthreads();

        // ---- fragments: lane l -> row/col (l&15), k = 8*(l>>4)+j ----
        bf16x8 fah[4], fal[4], fbh[4], fbl[4];
#pragma unroll
        for (int mf = 0; mf < 4; mf++) {
            const int off = (wm + mf * 16 + fr) * LDK + kg * 8;
            fah[mf] = *(const bf16x8*)&Ah[off];
            fal[mf] = *(const bf16x8*)&Al[off];
        }
#pragma unroll
        for (int nf = 0; nf < 4; nf++) {
            const int off = (wn + nf * 16 + fr) * LDK + kg * 8;
            fbh[nf] = *(const bf16x8*)&Bh[off];
            fbl[nf] = *(const bf16x8*)&Bl[off];
        }
        // ---- 3-term split MFMA ----
#pragma unroll
        for (int mf = 0; mf < 4; mf++) {
#pragma unroll
            for (int nf = 0; nf < 4; nf++) {
                acc[mf][nf] = __builtin_amdgcn_mfma_f32_16x16x32_bf16(
                    fah[mf], fbh[nf], acc[mf][nf], 0, 0, 0);
                acc[mf][nf] = __builtin_amdgcn_mfma_f32_16x16x32_bf16(
                    fah[mf], fbl[nf], acc[mf][nf], 0, 0, 0);
                acc[mf][nf] = __builtin_amdgcn_mfma_f32_16x16x32_bf16(
                    fal[mf], fbh[nf], acc[mf][nf], 0, 0, 0);
            }
        }
        __syncthreads();
    }

    // ---- epilogue: C/D layout col=lane&15, row=(lane>>4)*4+reg ----
    const float invs = 1.0f / sqrtf(1.0f + 1e-5f);
    const float av_ = (mode != 0) ? *a_ptr : 0.f;
#pragma unroll
    for (int nf = 0; nf < 4; nf++) {
        const int c = bn + wn + nf * 16 + fr;
        const float bi = bias[c];
        float gm = 0.f, bt = 0.f;
        if (mode != 0) { gm = gamma[c]; bt = beta2[c]; }
#pragma unroll
        for (int mf = 0; mf < 4; mf++) {
#pragma unroll
            for (int i = 0; i < 4; i++) {
                const int r = bm + wm + mf * 16 + kg * 4 + i;
                if (r < M) {
                    float h = acc[mf][nf][i] + bi;
                    if (mode != 0) {
                        h = gm * h * invs + bt;
                        h = (h >= 0.f) ? h : av_ * h;
                    }
                    float* cp = C + (size_t)r * N + c;
                    if (mode == 2) h += *cp;
                    *cp = h;
                }
            }
        }
    }
}

// ---------------------------------------------------------------------------
// CSR build: count -> deg -> scan -> fill
// ---------------------------------------------------------------------------
__global__ void count_k(const int* __restrict__ dst, int* __restrict__ counts)
{
    const int e = blockIdx.x * 256 + threadIdx.x;
    if (e < NE) atomicAdd(&counts[dst[e]], 1);
}

__global__ void deg_k(const int* __restrict__ counts, float* __restrict__ deg)
{
    const int i = blockIdx.x * 256 + threadIdx.x;
    if (i < NN) deg[i] = fmaxf((float)counts[i], 1.0f);
}

__global__ void __launch_bounds__(1024) scan_k(const int* __restrict__ counts,
                                               int* __restrict__ offs, int n)
{
    __shared__ int buf[1024];
    __shared__ int carry;
    const int t = threadIdx.x;
    if (t == 0) { carry = 0; offs[0] = 0; }
    __syncthreads();
    for (int base = 0; base < n; base += 1024) {
        const int i = base + t;
        int v = (i < n) ? counts[i] : 0;
        buf[t] = v;
        __syncthreads();
        for (int off = 1; off < 1024; off <<= 1) {
            int add = (t >= off) ? buf[t - off] : 0;
            __syncthreads();
            buf[t] += add;
            __syncthreads();
        }
        if (i < n) offs[i + 1] = carry + buf[t];
        __syncthreads();
        if (t == 0) carry += buf[1023];
        __syncthreads();
    }
}

__global__ void fill_k(const int* __restrict__ src, const int* __restrict__ dst,
                       const int* __restrict__ offs, int* __restrict__ cursor,
                       const float* __restrict__ deg,
                       int* __restrict__ csrc, float* __restrict__ cw)
{
    const int e = blockIdx.x * 256 + threadIdx.x;
    if (e < NE) {
        const int d = dst[e];
        const int s = src[e];
        const int p = atomicAdd(&cursor[d], 1);
        const int slot = offs[d] + p;
        csrc[slot] = s;
        cw[slot] = rsqrtf(deg[s] * deg[d]);
    }
}

// ---------------------------------------------------------------------------
// SpMV diffusion step: hout = (alpha*x + beta * A_norm @ hin) * scale
// 4 waves split neighbors mod 4; each lane owns a float4 of 4 columns
// (16 B/lane gather). Cross-wave reduction through LDS at the end.
// ---------------------------------------------------------------------------
__global__ void __launch_bounds__(256) spmv_k(
    const float* __restrict__ hin, const float* __restrict__ x,
    const int* __restrict__ offs, const int* __restrict__ csrc,
    const float* __restrict__ cw, float* __restrict__ hout, float scale)
{
    const int node = blockIdx.x;
    const int t = threadIdx.x;
    const int g = t >> 6;            // wave id 0..3 -> neighbor phase
    const int lane = t & 63;         // owns columns lane*4 .. lane*4+3
    const int start = offs[node], end = offs[node + 1];
    __shared__ int   ss[256];
    __shared__ float sw[256];
    __shared__ float part[4][256];
    float4 acc = make_float4(0.f, 0.f, 0.f, 0.f);
    for (int base = start; base < end; base += 256) {
        const int cnt = min(256, end - base);
        __syncthreads();
        if (t < cnt) { ss[t] = csrc[base + t]; sw[t] = cw[base + t]; }
        __syncthreads();
        for (int j = g; j < cnt; j += 4) {
            const float w = sw[j];
            const float4 v = *(const float4*)(hin + (size_t)ss[j] * HID + lane * 4);
            acc.x += v.x * w; acc.y += v.y * w;
            acc.z += v.z * w; acc.w += v.w * w;
        }
    }
    *(float4*)&part[g][lane * 4] = acc;
    __syncthreads();
    const float s = part[0][t] + part[1][t] + part[2][t] + part[3][t];
    const size_t o = (size_t)node * HID + t;
    hout[o] = (0.1f * x[o] + 0.9f * s) * scale;
}

// ---------------------------------------------------------------------------
// Precompute Wvo[k][h*256+j] = sum_d Wv[k][64h+d]*Wo[64h+d][j]
// ---------------------------------------------------------------------------
__global__ void build_wvo(const float* __restrict__ Wv, const float* __restrict__ Wo,
                          const float* __restrict__ bv,
                          float* __restrict__ Wvo, float* __restrict__ bvo)
{
    const int gid = blockIdx.x * 256 + threadIdx.x;
    if (gid < 256 * 1024) {
        const int k = gid >> 10;
        const int col = gid & 1023;
        const int h = col >> 8, j = col & 255;
        float s = 0.f;
#pragma unroll 8
        for (int d = 0; d < HD; d++)
            s += Wv[k * HID + h * HD + d] * Wo[(h * HD + d) * HID + j];
        Wvo[(size_t)k * 1024 + col] = s;
    } else if (gid < 256 * 1024 + 1024) {
        const int col = gid - 256 * 1024;
        const int h = col >> 8, j = col & 255;
        float s = 0.f;
#pragma unroll 8
        for (int d = 0; d < HD; d++)
            s += bv[h * HD + d] * Wo[(h * HD + d) * HID + j];
        bvo[col] = s;
    }
}

// ---------------------------------------------------------------------------
// Fused attention: per node, gather Cq/Ck rows, softmax(QK^T/8),
// z = attn @ P_gathered + bo + mem ; also emits final_h and logits.
// ---------------------------------------------------------------------------
__global__ void __launch_bounds__(256) attn_k(
    const float* __restrict__ Cq, const float* __restrict__ Ck,
    const float* __restrict__ P, const float* __restrict__ comb,
    const int* __restrict__ midx, const float* __restrict__ bo,
    const float* __restrict__ Wc, const float* __restrict__ bc,
    float* __restrict__ zout, float* __restrict__ fhout, float* __restrict__ lout)
{
    __shared__ float qs[16][260];
    __shared__ float ks[16][260];
    __shared__ float at[NH][16][16];
    __shared__ float row0[256];
    __shared__ int   idx[16];
    const int n = blockIdx.x;
    const int t = threadIdx.x;

    if (t < 16) idx[t] = (t == 0) ? n : midx[n * 15 + t - 1];
    __syncthreads();
#pragma unroll
    for (int r = 0; r < 16; r++) {
        const size_t g = (size_t)idx[r] * HID + t;
        qs[r][t] = Cq[g];
        ks[r][t] = Ck[g];
    }
    __syncthreads();

    const int kr = t & 15, qr = t >> 4;
#pragma unroll
    for (int h = 0; h < NH; h++) {
        float s = 0.f;
#pragma unroll
        for (int i = 0; i < HD; i++)
            s += qs[qr][h * HD + i] * ks[kr][h * HD + i];
        s *= 0.125f;
        float m = s;
        m = fmaxf(m, __shfl_xor(m, 1));
        m = fmaxf(m, __shfl_xor(m, 2));
        m = fmaxf(m, __shfl_xor(m, 4));
        m = fmaxf(m, __shfl_xor(m, 8));
        const float e = __expf(s - m);
        float sum = e;
        sum += __shfl_xor(sum, 1);
        sum += __shfl_xor(sum, 2);
        sum += __shfl_xor(sum, 4);
        sum += __shfl_xor(sum, 8);
        at[h][qr][kr] = e / sum;
    }
    __syncthreads();

    float acc[16];
#pragma unroll
    for (int q2 = 0; q2 < 16; q2++) acc[q2] = 0.f;
    for (int k2 = 0; k2 < 16; k2++) {
        const size_t base = (size_t)idx[k2] * 1024;
        const float p0 = P[base + t];
        const float p1 = P[base + 256 + t];
        const float p2 = P[base + 512 + t];
        const float p3 = P[base + 768 + t];
#pragma unroll
        for (int q2 = 0; q2 < 16; q2++) {
            acc[q2] += at[0][q2][k2] * p0 + at[1][q2][k2] * p1
                     + at[2][q2][k2] * p2 + at[3][q2][k2] * p3;
        }
    }
    const float bov = bo[t];
#pragma unroll
    for (int q2 = 0; q2 < 16; q2++) {
        const float val = acc[q2] + bov + comb[(size_t)idx[q2] * HID + t];
        zout[((size_t)n * 16 + q2) * HID + t] = val;
        if (q2 == 0) { row0[t] = val; fhout[(size_t)n * HID + t] = val; }
    }
    __syncthreads();
    if (t < 40) {
        float s = bc[t];
#pragma unroll 8
        for (int c = 0; c < 256; c++) s += row0[c] * Wc[c * 40 + t];
        lout[(size_t)n * 40 + t] = s;
    }
}

// ---------------------------------------------------------------------------
extern "C" void kernel_launch(void* const* d_in, const int* in_sizes, int n_in,
                              void* d_out, int out_size, void* d_ws, size_t ws_size,
                              hipStream_t stream)
{
    const float* text = (const float*)d_in[0];
    const float* vis  = (const float*)d_in[1];
    const int*   eidx = (const int*)d_in[2];
    const int*   midx = (const int*)d_in[3];
    const float* tW = (const float*)d_in[4];
    const float* tb = (const float*)d_in[5];
    const float* tg = (const float*)d_in[6];
    const float* tbe = (const float*)d_in[7];
    const float* ta = (const float*)d_in[8];
    const float* vW = (const float*)d_in[9];
    const float* vb = (const float*)d_in[10];
    const float* vg = (const float*)d_in[11];
    const float* vbe = (const float*)d_in[12];
    const float* va = (const float*)d_in[13];
    const float* Wq = (const float*)d_in[14];
    const float* bq = (const float*)d_in[15];
    const float* Wk = (const float*)d_in[16];
    const float* bk = (const float*)d_in[17];
    const float* Wv = (const float*)d_in[18];
    const float* bv = (const float*)d_in[19];
    const float* Wo = (const float*)d_in[20];
    const float* bo = (const float*)d_in[21];
    const float* Wc = (const float*)d_in[22];
    const float* bc = (const float*)d_in[23];

    float* out_logits = (float*)d_out;
    float* out_fh = out_logits + (size_t)NN * 40;
    float* out_z  = out_fh + (size_t)NN * HID;

    const size_t SLOT = (size_t)NN * HID;
    float* s_x   = (float*)d_ws;
    float* s_h1  = s_x + SLOT;
    float* s_h2  = s_h1 + SLOT;
    float* s_cq  = s_h2 + SLOT;
    float* s_ck  = s_cq + SLOT;
    float* s_P   = s_ck + SLOT;                 // NN x 1024
    float* s_wvo = s_P + (size_t)NN * 1024;     // 256 x 1024
    float* s_bvo = s_wvo + 256 * 1024;          // 1024
    float* c_deg = s_bvo + 1024;                // NN floats
    int* c_counts = (int*)(c_deg + NN);
    int* c_off    = c_counts + NN;              // NN+1
    int* c_cursor = c_off + (NN + 1);
    int* c_src    = c_cursor + NN;              // NE
    float* c_w    = (float*)(c_src + NE);       // NE

    const int* e_src = eidx;
    const int* e_dst = eidx + NE;

    hipMemsetAsync(c_counts, 0, NN * sizeof(int), stream);
    hipMemsetAsync(c_cursor, 0, NN * sizeof(int), stream);

    // ---- phase-1 weight splits live in s_h1 (dead until first spmv write) ----
    unsigned short* tWh = (unsigned short*)s_h1;
    unsigned short* tWl = tWh + 768 * 256;
    unsigned short* vWh = tWl + 768 * 256;
    unsigned short* vWl = vWh + 512 * 256;
    wsplit_k<<<768, 256, 0, stream>>>(tW, 768, 256, tWh, tWl);
    wsplit_k<<<512, 256, 0, stream>>>(vW, 512, 256, vWh, vWl);

    const dim3 gE(HID / TBN, (NN + TBM - 1) / TBM);

    // encoders: x = leaky_bn(text@tW) + leaky_bn(vis@vW)  (bf16-split MFMA)
    gemm_mfma<<<gE, 256, 0, stream>>>(text, tWh, tWl, tb, tg, tbe, ta, s_x, NN, HID, 768, 1);
    gemm_mfma<<<gE, 256, 0, stream>>>(vis,  vWh, vWl, vb, vg, vbe, va, s_x, NN, HID, 512, 2);

    // CSR build
    count_k<<<NE / 256, 256, 0, stream>>>(e_dst, c_counts);
    deg_k<<<(NN + 255) / 256, 256, 0, stream>>>(c_counts, c_deg);
    scan_k<<<1, 1024, 0, stream>>>(c_counts, c_off, NN);
    fill_k<<<NE / 256, 256, 0, stream>>>(e_src, e_dst, c_off, c_cursor, c_deg, c_src, c_w);

    // diffusion
    const double beta_k = 0.9 * 0.9 * 0.9 * 0.9;
    const double zd = 0.1 * (1.0 - beta_k) / (1.0 - 0.9) + beta_k;
    const float invz = (float)(1.0 / zd);
    spmv_k<<<NN, 256, 0, stream>>>(s_x,  s_x, c_off, c_src, c_w, s_h1, 1.0f);
    spmv_k<<<NN, 256, 0, stream>>>(s_h1, s_x, c_off, c_src, c_w, s_h2, 1.0f);
    spmv_k<<<NN, 256, 0, stream>>>(s_h2, s_x, c_off, c_src, c_w, s_h1, 1.0f);
    spmv_k<<<NN, 256, 0, stream>>>(s_h1, s_x, c_off, c_src, c_w, s_h2, invz); // s_h2 = combined

    // ---- phase-2 weight splits reuse s_h1 (dead after last spmv) ----
    unsigned short* qWh = (unsigned short*)s_h1;
    unsigned short* qWl = qWh + 256 * 256;
    unsigned short* kWh = qWl + 256 * 256;
    unsigned short* kWl = kWh + 256 * 256;
    unsigned short* pWh = kWl + 256 * 256;
    unsigned short* pWl = pWh + 256 * 1024;
    wsplit_k<<<256, 256, 0, stream>>>(Wq, 256, 256, qWh, qWl);
    wsplit_k<<<256, 256, 0, stream>>>(Wk, 256, 256, kWh, kWl);
    build_wvo<<<(256 * 1024 + 1024) / 256, 256, 0, stream>>>(Wv, Wo, bv, s_wvo, s_bvo);
    wsplit_k<<<1024, 256, 0, stream>>>(s_wvo, 256, 1024, pWh, pWl);

    // MHA projections (bf16-split MFMA)
    gemm_mfma<<<gE, 256, 0, stream>>>(s_h2, qWh, qWl, bq, nullptr, nullptr, nullptr, s_cq, NN, HID, HID, 0);
    gemm_mfma<<<gE, 256, 0, stream>>>(s_h2, kWh, kWl, bk, nullptr, nullptr, nullptr, s_ck, NN, HID, HID, 0);
    const dim3 gP(1024 / TBN, (NN + TBM - 1) / TBM);
    gemm_mfma<<<gP, 256, 0, stream>>>(s_h2, pWh, pWl, s_bvo, nullptr, nullptr, nullptr, s_P, NN, 1024, HID, 0);

    // fused attention + epilogue + logits
    attn_k<<<NN, 256, 0, stream>>>(s_cq, s_ck, s_P, s_h2, midx, bo, Wc, bc,
                                   out_z, out_fh, out_logits);
}

// Round 8
// 2275.286 us; speedup vs baseline: 1.0350x; 1.0350x over previous
//
#include <hip/hip_runtime.h>
#include <math.h>

#define NN 30000
#define NE 960000
#define HID 256
#define NH 4
#define HD 64

typedef __attribute__((ext_vector_type(8))) __bf16 bf16x8;
typedef __attribute__((ext_vector_type(4))) float f32x4;
typedef __attribute__((ext_vector_type(4))) unsigned int u32x4;
typedef __attribute__((ext_vector_type(4))) unsigned short u16x4;

__device__ __forceinline__ unsigned short f2bf(float f) {
    unsigned u = __builtin_bit_cast(unsigned, f);
    u += 0x7fffu + ((u >> 16) & 1u);          // round-to-nearest-even
    return (unsigned short)(u >> 16);
}
__device__ __forceinline__ float bf2f(unsigned short h) {
    unsigned u = ((unsigned)h) << 16;
    return __builtin_bit_cast(float, u);
}

// ---------------------------------------------------------------------------
// Weight split+transpose: W (K x N fp32, row-major) -> Wh/Wl (N x K bf16,
// row-major, k contiguous).  W = Wh + Wl to ~2^-17 relative.
// ---------------------------------------------------------------------------
__global__ void wsplit_k(const float* __restrict__ W, int K, int N,
                         unsigned short* __restrict__ Wh,
                         unsigned short* __restrict__ Wl)
{
    const int gid = blockIdx.x * 256 + threadIdx.x;
    if (gid >= K * N) return;
    const int k = gid / N, n = gid - k * N;
    const float f = W[gid];
    const unsigned short h = f2bf(f);
    const float lo = f - bf2f(h);
    Wh[(size_t)n * K + k] = h;
    Wl[(size_t)n * K + k] = f2bf(lo);
}

// ---------------------------------------------------------------------------
// bf16-split MFMA GEMM: C = A@W + epilogue, fp32 in/out, internally
// A@W ~= Ah@Wh + Ah@Wl + Al@Wh via v_mfma_f32_16x16x32_bf16 (fp32 accum).
// Tile 128x128, BK=32, 256 threads = 4 waves in 2x2, each wave 64x64
// (4x4 fragments of 16x16).
// mode 0: C = A@W + bias
// mode 1: C = leaky(gamma*(A@W+bias)*invs + beta2, a)
// mode 2: C += leaky(...)
// Requires: K % 32 == 0, N % 128 == 0 (true for all call sites).
// ---------------------------------------------------------------------------
#define TBM 128
#define TBN 128
#define TBK 32
#define LDK 40   // padded k-stride (elements): 80 B rows, 16B-aligned, ~2-way banks

__global__ void __launch_bounds__(256) gemm_mfma(
    const float* __restrict__ A,
    const unsigned short* __restrict__ Wth,   // N x K bf16 hi
    const unsigned short* __restrict__ Wtl,   // N x K bf16 lo
    const float* __restrict__ bias,
    const float* __restrict__ gamma, const float* __restrict__ beta2,
    const float* __restrict__ a_ptr,
    float* __restrict__ C, int M, int N, int K, int mode)
{
    __shared__ unsigned short Ah[TBM * LDK];
    __shared__ unsigned short Al[TBM * LDK];
    __shared__ unsigned short Bh[TBN * LDK];
    __shared__ unsigned short Bl[TBN * LDK];

    const int t = threadIdx.x;
    const int bm = blockIdx.y * TBM;
    const int bn = blockIdx.x * TBN;
    const int wid = t >> 6, lane = t & 63;
    const int wm = (wid >> 1) * 64;           // wave row offset in tile
    const int wn = (wid & 1) * 64;            // wave col offset in tile
    const int fr = lane & 15;                 // fragment row/col within 16
    const int kg = lane >> 4;                 // k-group 0..3 (8 k each)

    const int arow = t >> 3;                  // 0..31  (A staging)
    const int ak   = (t & 7) * 4;             // 0..28

    f32x4 acc[4][4] = {};

    for (int k0 = 0; k0 < K; k0 += TBK) {
        // ---- stage A tile (fp32 -> bf16 hi/lo) ----
#pragma unroll
        for (int r = 0; r < 4; r++) {
            const int row = r * 32 + arow;
            const int gr = bm + row;
            float4 av = make_float4(0.f, 0.f, 0.f, 0.f);
            if (gr < M) av = *(const float4*)(A + (size_t)gr * K + k0 + ak);
            const unsigned short h0 = f2bf(av.x), h1 = f2bf(av.y),
                                 h2 = f2bf(av.z), h3 = f2bf(av.w);
            const unsigned short l0 = f2bf(av.x - bf2f(h0)),
                                 l1 = f2bf(av.y - bf2f(h1)),
                                 l2 = f2bf(av.z - bf2f(h2)),
                                 l3 = f2bf(av.w - bf2f(h3));
            u16x4 hv; hv.x = h0; hv.y = h1; hv.z = h2; hv.w = h3;
            u16x4 lv; lv.x = l0; lv.y = l1; lv.z = l2; lv.w = l3;
            *(u16x4*)&Ah[row * LDK + ak] = hv;
            *(u16x4*)&Al[row * LDK + ak] = lv;
        }
        // ---- stage B tile (already bf16, transposed [n][k]) ----
#pragma unroll
        for (int i2 = 0; i2 < 2; i2++) {
            const int i = i2 * 256 + t;
            const int n = i >> 2, kc = (i & 3) * 8;
            const size_t g = (size_t)(bn + n) * K + k0 + kc;
            *(u32x4*)&Bh[n * LDK + kc] = *(const u32x4*)&Wth[g];
            *(u32x4*)&Bl[n * LDK + kc] = *(const u32x4*)&Wtl[g];
        }
        __syncthreads();

        // ---- fragments: lane l -> row/col (l&15), k = 8*(l>>4)+j ----
        bf16x8 fah[4], fal[4], fbh[4], fbl[4];
#pragma unroll
        for (int mf = 0; mf < 4; mf++) {
            const int off = (wm + mf * 16 + fr) * LDK + kg * 8;
            fah[mf] = *(const bf16x8*)&Ah[off];
            fal[mf] = *(const bf16x8*)&Al[off];
        }
#pragma unroll
        for (int nf = 0; nf < 4; nf++) {
            const int off = (wn + nf * 16 + fr) * LDK + kg * 8;
            fbh[nf] = *(const bf16x8*)&Bh[off];
            fbl[nf] = *(const bf16x8*)&Bl[off];
        }
        // ---- 3-term split MFMA ----
#pragma unroll
        for (int mf = 0; mf < 4; mf++) {
#pragma unroll
            for (int nf = 0; nf < 4; nf++) {
                acc[mf][nf] = __builtin_amdgcn_mfma_f32_16x16x32_bf16(
                    fah[mf], fbh[nf], acc[mf][nf], 0, 0, 0);
                acc[mf][nf] = __builtin_amdgcn_mfma_f32_16x16x32_bf16(
                    fah[mf], fbl[nf], acc[mf][nf], 0, 0, 0);
                acc[mf][nf] = __builtin_amdgcn_mfma_f32_16x16x32_bf16(
                    fal[mf], fbh[nf], acc[mf][nf], 0, 0, 0);
            }
        }
        __syncthreads();
    }

    // ---- epilogue: C/D layout col=lane&15, row=(lane>>4)*4+reg ----
    const float invs = 1.0f / sqrtf(1.0f + 1e-5f);
    const float av_ = (mode != 0) ? *a_ptr : 0.f;
#pragma unroll
    for (int nf = 0; nf < 4; nf++) {
        const int c = bn + wn + nf * 16 + fr;
        const float bi = bias[c];
        float gm = 0.f, bt = 0.f;
        if (mode != 0) { gm = gamma[c]; bt = beta2[c]; }
#pragma unroll
        for (int mf = 0; mf < 4; mf++) {
#pragma unroll
            for (int i = 0; i < 4; i++) {
                const int r = bm + wm + mf * 16 + kg * 4 + i;
                if (r < M) {
                    float h = acc[mf][nf][i] + bi;
                    if (mode != 0) {
                        h = gm * h * invs + bt;
                        h = (h >= 0.f) ? h : av_ * h;
                    }
                    float* cp = C + (size_t)r * N + c;
                    if (mode == 2) h += *cp;
                    *cp = h;
                }
            }
        }
    }
}

// ---------------------------------------------------------------------------
// CSR build: count -> deg -> scan -> fill
// ---------------------------------------------------------------------------
__global__ void count_k(const int* __restrict__ dst, int* __restrict__ counts)
{
    const int e = blockIdx.x * 256 + threadIdx.x;
    if (e < NE) atomicAdd(&counts[dst[e]], 1);
}

__global__ void deg_k(const int* __restrict__ counts, float* __restrict__ deg)
{
    const int i = blockIdx.x * 256 + threadIdx.x;
    if (i < NN) deg[i] = fmaxf((float)counts[i], 1.0f);
}

__global__ void __launch_bounds__(1024) scan_k(const int* __restrict__ counts,
                                               int* __restrict__ offs, int n)
{
    __shared__ int buf[1024];
    __shared__ int carry;
    const int t = threadIdx.x;
    if (t == 0) { carry = 0; offs[0] = 0; }
    __syncthreads();
    for (int base = 0; base < n; base += 1024) {
        const int i = base + t;
        int v = (i < n) ? counts[i] : 0;
        buf[t] = v;
        __syncthreads();
        for (int off = 1; off < 1024; off <<= 1) {
            int add = (t >= off) ? buf[t - off] : 0;
            __syncthreads();
            buf[t] += add;
            __syncthreads();
        }
        if (i < n) offs[i + 1] = carry + buf[t];
        __syncthreads();
        if (t == 0) carry += buf[1023];
        __syncthreads();
    }
}

__global__ void fill_k(const int* __restrict__ src, const int* __restrict__ dst,
                       const int* __restrict__ offs, int* __restrict__ cursor,
                       const float* __restrict__ deg,
                       int* __restrict__ csrc, float* __restrict__ cw)
{
    const int e = blockIdx.x * 256 + threadIdx.x;
    if (e < NE) {
        const int d = dst[e];
        const int s = src[e];
        const int p = atomicAdd(&cursor[d], 1);
        const int slot = offs[d] + p;
        csrc[slot] = s;
        cw[slot] = rsqrtf(deg[s] * deg[d]);
    }
}

// ---------------------------------------------------------------------------
// SpMV diffusion step: hout = (alpha*x + beta * A_norm @ hin) * scale
// 4 waves split neighbors mod 4; each lane owns a float4 of 4 columns
// (16 B/lane gather). Cross-wave reduction through LDS at the end.
// ---------------------------------------------------------------------------
__global__ void __launch_bounds__(256) spmv_k(
    const float* __restrict__ hin, const float* __restrict__ x,
    const int* __restrict__ offs, const int* __restrict__ csrc,
    const float* __restrict__ cw, float* __restrict__ hout, float scale)
{
    const int node = blockIdx.x;
    const int t = threadIdx.x;
    const int g = t >> 6;            // wave id 0..3 -> neighbor phase
    const int lane = t & 63;         // owns columns lane*4 .. lane*4+3
    const int start = offs[node], end = offs[node + 1];
    __shared__ int   ss[256];
    __shared__ float sw[256];
    __shared__ float part[4][256];
    float4 acc = make_float4(0.f, 0.f, 0.f, 0.f);
    for (int base = start; base < end; base += 256) {
        const int cnt = min(256, end - base);
        __syncthreads();
        if (t < cnt) { ss[t] = csrc[base + t]; sw[t] = cw[base + t]; }
        __syncthreads();
        for (int j = g; j < cnt; j += 4) {
            const float w = sw[j];
            const float4 v = *(const float4*)(hin + (size_t)ss[j] * HID + lane * 4);
            acc.x += v.x * w; acc.y += v.y * w;
            acc.z += v.z * w; acc.w += v.w * w;
        }
    }
    *(float4*)&part[g][lane * 4] = acc;
    __syncthreads();
    const float s = part[0][t] + part[1][t] + part[2][t] + part[3][t];
    const size_t o = (size_t)node * HID + t;
    hout[o] = (0.1f * x[o] + 0.9f * s) * scale;
}

// ---------------------------------------------------------------------------
// Precompute Wvo[k][h*256+j] = sum_d Wv[k][64h+d]*Wo[64h+d][j]
// ---------------------------------------------------------------------------
__global__ void build_wvo(const float* __restrict__ Wv, const float* __restrict__ Wo,
                          const float* __restrict__ bv,
                          float* __restrict__ Wvo, float* __restrict__ bvo)
{
    const int gid = blockIdx.x * 256 + threadIdx.x;
    if (gid < 256 * 1024) {
        const int k = gid >> 10;
        const int col = gid & 1023;
        const int h = col >> 8, j = col & 255;
        float s = 0.f;
#pragma unroll 8
        for (int d = 0; d < HD; d++)
            s += Wv[k * HID + h * HD + d] * Wo[(h * HD + d) * HID + j];
        Wvo[(size_t)k * 1024 + col] = s;
    } else if (gid < 256 * 1024 + 1024) {
        const int col = gid - 256 * 1024;
        const int h = col >> 8, j = col & 255;
        float s = 0.f;
#pragma unroll 8
        for (int d = 0; d < HD; d++)
            s += bv[h * HD + d] * Wo[(h * HD + d) * HID + j];
        bvo[col] = s;
    }
}

// ---------------------------------------------------------------------------
// Fused attention: per node, gather Cq/Ck rows, softmax(QK^T/8),
// z = attn @ P_gathered + bo + mem ; also emits final_h and logits.
// v2: P/comb gathers hoisted to registers (one MLP window, hidden under the
// score phase); at relayout [q][h][k] -> 16 broadcast ds_read_b128 per q-row
// instead of 64 scalar ds_read_b32 (4x fewer LDS ops); PV fully unrolled
// with static register indexing.
// ---------------------------------------------------------------------------
__global__ void __launch_bounds__(256) attn_k(
    const float* __restrict__ Cq, const float* __restrict__ Ck,
    const float* __restrict__ P, const float* __restrict__ comb,
    const int* __restrict__ midx, const float* __restrict__ bo,
    const float* __restrict__ Wc, const float* __restrict__ bc,
    float* __restrict__ zout, float* __restrict__ fhout, float* __restrict__ lout)
{
    __shared__ float qs[16][260];     // +4 pad breaks 256-stride bank conflicts
    __shared__ float ks[16][260];
    __shared__ float at2[16][NH][16]; // [q][h][k]: 64 contiguous floats per q-row
    __shared__ float row0[256];
    __shared__ int   idx[16];
    const int n = blockIdx.x;
    const int t = threadIdx.x;

    if (t < 16) idx[t] = (t == 0) ? n : midx[n * 15 + t - 1];
    __syncthreads();
    int idr[16];
#pragma unroll
    for (int r = 0; r < 16; r++) idr[r] = idx[r];
#pragma unroll
    for (int r = 0; r < 16; r++) {
        const size_t g = (size_t)idr[r] * HID + t;
        qs[r][t] = Cq[g];
        ks[r][t] = Ck[g];
    }

    // issue all P / comb gathers now: 80 loads in one latency window,
    // results consumed only after the score phase (waitcnt at first use)
    float pv[16][4];
#pragma unroll
    for (int k2 = 0; k2 < 16; k2++) {
        const float* pb = P + (size_t)idr[k2] * 1024 + t;
        pv[k2][0] = pb[0];
        pv[k2][1] = pb[256];
        pv[k2][2] = pb[512];
        pv[k2][3] = pb[768];
    }
    float cmb[16];
#pragma unroll
    for (int q2 = 0; q2 < 16; q2++)
        cmb[q2] = comb[(size_t)idr[q2] * HID + t];
    const float bov = bo[t];

    __syncthreads();                  // qs/ks staged

    const int kr = t & 15, qr = t >> 4;   // 256 threads = 16 q-rows x 16 k-rows
#pragma unroll
    for (int h = 0; h < NH; h++) {
        float s = 0.f;
#pragma unroll
        for (int i = 0; i < HD; i++)
            s += qs[qr][h * HD + i] * ks[kr][h * HD + i];
        s *= 0.125f;                       // 1/sqrt(64)
        float m = s;
        m = fmaxf(m, __shfl_xor(m, 1));
        m = fmaxf(m, __shfl_xor(m, 2));
        m = fmaxf(m, __shfl_xor(m, 4));
        m = fmaxf(m, __shfl_xor(m, 8));
        const float e = __expf(s - m);
        float sum = e;
        sum += __shfl_xor(sum, 1);
        sum += __shfl_xor(sum, 2);
        sum += __shfl_xor(sum, 4);
        sum += __shfl_xor(sum, 8);
        at2[qr][h][kr] = e / sum;
    }
    __syncthreads();                  // at2 ready

    // PV: thread t = column; P resident in registers, at via broadcast b128
    float acc[16];
#pragma unroll
    for (int q2 = 0; q2 < 16; q2++) acc[q2] = cmb[q2] + bov;

#pragma unroll
    for (int q2 = 0; q2 < 16; q2++) {
        float s = acc[q2];
#pragma unroll
        for (int h = 0; h < NH; h++) {
            const f32x4* ap = (const f32x4*)&at2[q2][h][0];
            const f32x4 a0 = ap[0], a1 = ap[1], a2 = ap[2], a3 = ap[3];
            s += a0.x * pv[0][h]  + a0.y * pv[1][h]  + a0.z * pv[2][h]  + a0.w * pv[3][h]
               + a1.x * pv[4][h]  + a1.y * pv[5][h]  + a1.z * pv[6][h]  + a1.w * pv[7][h]
               + a2.x * pv[8][h]  + a2.y * pv[9][h]  + a2.z * pv[10][h] + a2.w * pv[11][h]
               + a3.x * pv[12][h] + a3.y * pv[13][h] + a3.z * pv[14][h] + a3.w * pv[15][h];
        }
        acc[q2] = s;
    }

#pragma unroll
    for (int q2 = 0; q2 < 16; q2++)
        zout[((size_t)n * 16 + q2) * HID + t] = acc[q2];
    row0[t] = acc[0];
    fhout[(size_t)n * HID + t] = acc[0];
    __syncthreads();
    if (t < 40) {
        float s = bc[t];
#pragma unroll 8
        for (int c = 0; c < 256; c++) s += row0[c] * Wc[c * 40 + t];
        lout[(size_t)n * 40 + t] = s;
    }
}

// ---------------------------------------------------------------------------
extern "C" void kernel_launch(void* const* d_in, const int* in_sizes, int n_in,
                              void* d_out, int out_size, void* d_ws, size_t ws_size,
                              hipStream_t stream)
{
    const float* text = (const float*)d_in[0];
    const float* vis  = (const float*)d_in[1];
    const int*   eidx = (const int*)d_in[2];
    const int*   midx = (const int*)d_in[3];
    const float* tW = (const float*)d_in[4];
    const float* tb = (const float*)d_in[5];
    const float* tg = (const float*)d_in[6];
    const float* tbe = (const float*)d_in[7];
    const float* ta = (const float*)d_in[8];
    const float* vW = (const float*)d_in[9];
    const float* vb = (const float*)d_in[10];
    const float* vg = (const float*)d_in[11];
    const float* vbe = (const float*)d_in[12];
    const float* va = (const float*)d_in[13];
    const float* Wq = (const float*)d_in[14];
    const float* bq = (const float*)d_in[15];
    const float* Wk = (const float*)d_in[16];
    const float* bk = (const float*)d_in[17];
    const float* Wv = (const float*)d_in[18];
    const float* bv = (const float*)d_in[19];
    const float* Wo = (const float*)d_in[20];
    const float* bo = (const float*)d_in[21];
    const float* Wc = (const float*)d_in[22];
    const float* bc = (const float*)d_in[23];

    float* out_logits = (float*)d_out;
    float* out_fh = out_logits + (size_t)NN * 40;
    float* out_z  = out_fh + (size_t)NN * HID;

    const size_t SLOT = (size_t)NN * HID;
    float* s_x   = (float*)d_ws;
    float* s_h1  = s_x + SLOT;
    float* s_h2  = s_h1 + SLOT;
    float* s_cq  = s_h2 + SLOT;
    float* s_ck  = s_cq + SLOT;
    float* s_P   = s_ck + SLOT;                 // NN x 1024
    float* s_wvo = s_P + (size_t)NN * 1024;     // 256 x 1024
    float* s_bvo = s_wvo + 256 * 1024;          // 1024
    float* c_deg = s_bvo + 1024;                // NN floats
    int* c_counts = (int*)(c_deg + NN);
    int* c_off    = c_counts + NN;              // NN+1
    int* c_cursor = c_off + (NN + 1);
    int* c_src    = c_cursor + NN;              // NE
    float* c_w    = (float*)(c_src + NE);       // NE

    const int* e_src = eidx;
    const int* e_dst = eidx + NE;

    hipMemsetAsync(c_counts, 0, NN * sizeof(int), stream);
    hipMemsetAsync(c_cursor, 0, NN * sizeof(int), stream);

    // ---- phase-1 weight splits live in s_h1 (dead until first spmv write) ----
    unsigned short* tWh = (unsigned short*)s_h1;
    unsigned short* tWl = tWh + 768 * 256;
    unsigned short* vWh = tWl + 768 * 256;
    unsigned short* vWl = vWh + 512 * 256;
    wsplit_k<<<768, 256, 0, stream>>>(tW, 768, 256, tWh, tWl);
    wsplit_k<<<512, 256, 0, stream>>>(vW, 512, 256, vWh, vWl);

    const dim3 gE(HID / TBN, (NN + TBM - 1) / TBM);

    // encoders: x = leaky_bn(text@tW) + leaky_bn(vis@vW)  (bf16-split MFMA)
    gemm_mfma<<<gE, 256, 0, stream>>>(text, tWh, tWl, tb, tg, tbe, ta, s_x, NN, HID, 768, 1);
    gemm_mfma<<<gE, 256, 0, stream>>>(vis,  vWh, vWl, vb, vg, vbe, va, s_x, NN, HID, 512, 2);

    // CSR build
    count_k<<<NE / 256, 256, 0, stream>>>(e_dst, c_counts);
    deg_k<<<(NN + 255) / 256, 256, 0, stream>>>(c_counts, c_deg);
    scan_k<<<1, 1024, 0, stream>>>(c_counts, c_off, NN);
    fill_k<<<NE / 256, 256, 0, stream>>>(e_src, e_dst, c_off, c_cursor, c_deg, c_src, c_w);

    // diffusion
    const double beta_k = 0.9 * 0.9 * 0.9 * 0.9;
    const double zd = 0.1 * (1.0 - beta_k) / (1.0 - 0.9) + beta_k;
    const float invz = (float)(1.0 / zd);
    spmv_k<<<NN, 256, 0, stream>>>(s_x,  s_x, c_off, c_src, c_w, s_h1, 1.0f);
    spmv_k<<<NN, 256, 0, stream>>>(s_h1, s_x, c_off, c_src, c_w, s_h2, 1.0f);
    spmv_k<<<NN, 256, 0, stream>>>(s_h2, s_x, c_off, c_src, c_w, s_h1, 1.0f);
    spmv_k<<<NN, 256, 0, stream>>>(s_h1, s_x, c_off, c_src, c_w, s_h2, invz); // s_h2 = combined

    // ---- phase-2 weight splits reuse s_h1 (dead after last spmv) ----
    unsigned short* qWh = (unsigned short*)s_h1;
    unsigned short* qWl = qWh + 256 * 256;
    unsigned short* kWh = qWl + 256 * 256;
    unsigned short* kWl = kWh + 256 * 256;
    unsigned short* pWh = kWl + 256 * 256;
    unsigned short* pWl = pWh + 256 * 1024;
    wsplit_k<<<256, 256, 0, stream>>>(Wq, 256, 256, qWh, qWl);
    wsplit_k<<<256, 256, 0, stream>>>(Wk, 256, 256, kWh, kWl);
    build_wvo<<<(256 * 1024 + 1024) / 256, 256, 0, stream>>>(Wv, Wo, bv, s_wvo, s_bvo);
    wsplit_k<<<1024, 256, 0, stream>>>(s_wvo, 256, 1024, pWh, pWl);

    // MHA projections (bf16-split MFMA)
    gemm_mfma<<<gE, 256, 0, stream>>>(s_h2, qWh, qWl, bq, nullptr, nullptr, nullptr, s_cq, NN, HID, HID, 0);
    gemm_mfma<<<gE, 256, 0, stream>>>(s_h2, kWh, kWl, bk, nullptr, nullptr, nullptr, s_ck, NN, HID, HID, 0);
    const dim3 gP(1024 / TBN, (NN + TBM - 1) / TBM);
    gemm_mfma<<<gP, 256, 0, stream>>>(s_h2, pWh, pWl, s_bvo, nullptr, nullptr, nullptr, s_P, NN, 1024, HID, 0);

    // fused attention + epilogue + logits
    attn_k<<<NN, 256, 0, stream>>>(s_cq, s_ck, s_P, s_h2, midx, bo, Wc, bc,
                                   out_z, out_fh, out_logits);
}